// Round 12
// baseline (19009.323 us; speedup 1.0000x reference)
//
#include <hip/hip_runtime.h>
#include <stdint.h>

// ---------------------------------------------------------------------------
// 2-layer BiLSTM LM: emb -> BiLSTM(E=256->H=512) -> BiLSTM(1024->512) -> proj
// V=128 E=256 H=512 B=128 T=512.
//
// Round 12 (r11 post-mortem: XCC_ID-based cliques deadlocked -- placement
// discovery + same-XCD sc0 flags are unproven under this harness; reverted
// to agent/LLC mechanics proven in r8-r10):
//  - dual-direction interleave: 128 WGs = (q batch-quarter, nb16 unit-block),
//    each WG runs fwd AND bwd chains alternately -> each chain's barrier
//    publish/observe latency hides under the other chain's work.
//  - barrier scope = 32 WGs (same q): consumer needs only same-q producers.
//    agent-scope slot flags (r8-proven), sc1 h exchange (r9-proven),
//    NO cache invalidates anywhere in the step loop.
//  - waves = (m-tile, plane): kh=0 computes Whh*h_hi, kh=1 Whh*h_lo ->
//    no duplicated h reads; partials summed via the LDS gate exchange.
//  - Whh both dirs LDS-resident (128KB). L0 x inline (Wih0 L2-hot).
//    L1 x: 8-step bulk precompute in shadow (Wih streamed 1x/window,
//    bf16 partials in global xw, same-thread produce/consume).
//  - proj every 32 ticks, 16 chunks, write/add pairing kf+kb=15 (r10-style).
//
// Numerics (r1..r10 validated): bf16 MFMA fp32-accum; c f32; h hi/lo planes.
// ---------------------------------------------------------------------------

#define TT 512
#define BB 128
#define HH 512
#define VV 128
#define AGENT __HIP_MEMORY_SCOPE_AGENT

typedef __attribute__((ext_vector_type(8))) short bf16x8;
typedef __attribute__((ext_vector_type(4))) float f32x4;

__device__ __forceinline__ ushort f2bf(float f) {
  uint32_t u = __builtin_bit_cast(uint32_t, f);
  u += 0x7FFFu + ((u >> 16) & 1u);
  return (ushort)(u >> 16);
}
__device__ __forceinline__ float bf2f(ushort h) {
  uint32_t u = ((uint32_t)h) << 16;
  return __builtin_bit_cast(float, u);
}
__device__ __forceinline__ float sigm(float x) { return 1.f / (1.f + __expf(-x)); }
__device__ __forceinline__ float tanh_f(float x) { return 1.f - 2.f / (__expf(2.f * x) + 1.f); }
__device__ __forceinline__ bf16x8 bc8u(uint4 u) { return __builtin_bit_cast(bf16x8, u); }

__global__ __launch_bounds__(256) void report_ws(float* __restrict__ out, int n, float val) {
  int i = blockIdx.x * 256 + threadIdx.x;
  if (i < n) out[i] = val;
}

__global__ __launch_bounds__(256) void pack_emb(const float* __restrict__ emb,
                                                ushort* __restrict__ embB) {
  int i = blockIdx.x * 256 + threadIdx.x;  // 32768
  embB[i] = f2bf(emb[i]);
}

// Frag pack: Wp[d][nb16][ks S][g 4][512]; elem (l,e):
//   grow = g*512 + nb16*16 + (l&15);  k = ks*32 + (l>>4)*8 + e;  val = W[d][grow][k]
__global__ __launch_bounds__(256) void pack_w(const float* __restrict__ W,
                                              ushort* __restrict__ Wp,
                                              int S, int K) {
  size_t idx = (size_t)blockIdx.x * 256 + threadIdx.x;
  size_t total = (size_t)2 * 32 * S * 2048;
  if (idx >= total) return;
  int e = (int)(idx & 7);
  int l = (int)((idx >> 3) & 63);
  int g = (int)((idx >> 9) & 3);
  int ks = (int)((idx >> 11) % (size_t)S);
  int slice = (int)(idx / ((size_t)S << 11));
  int nb16 = slice & 31, d = slice >> 5;
  int grow = g * 512 + nb16 * 16 + (l & 15);
  int k = ks * 32 + (l >> 4) * 8 + e;
  Wp[idx] = f2bf(W[((size_t)d * 2048 + grow) * K + k]);
}

__global__ __launch_bounds__(256) void pack_wout(const float* __restrict__ Wo,
                                                 ushort* __restrict__ WoB) {
  int i = blockIdx.x * 256 + threadIdx.x;  // 131072
  WoB[i] = f2bf(Wo[i]);
}

// zero hpk (2MB = 131072 uint4, grid 512) + barrier slots (512 u32)
__global__ __launch_bounds__(256) void zero_h(unsigned int* __restrict__ hpk,
                                              unsigned int* __restrict__ bars) {
  int i = blockIdx.x * 256 + threadIdx.x;
  ((uint4*)hpk)[i] = make_uint4(0, 0, 0, 0);
  if (i < 512) bars[i] = 0;
}

// ---------------------------------------------------------------------------
// Projection chunk k (16 total). WG -> dirp=wg&1, tslot=(wg>>1)&31, bh=wg>>6.
// tile: rows bh*64..+64, all 128 v, K=512 (dirp half of Wout).
// k<8: out = acc + bout (write); k>=8: out += acc (atomic).
// ring read via sc1 u64 atomics (r9-proven). BK=32, 12KB LDS.
// ---------------------------------------------------------------------------
__device__ void proj_body(int k, int wg, int tid, const ushort* __restrict__ ring,
                          const ushort* __restrict__ WoB,
                          const float* __restrict__ bout,
                          float* __restrict__ out, char* shm) {
  const int dirp = wg & 1;
  const int tslot = (wg >> 1) & 31;
  const int bh = wg >> 6;
  const int tp = (dirp ? (480 - 32 * k) : (32 * k)) + tslot;
  const int mode = (k >= 8);
  ushort* As = (ushort*)shm;            // [64][32] swizzled
  ushort* Bs = (ushort*)(shm + 4096);   // [128][32] swizzled
  const int wm = tid >> 6;
  const int lane = tid & 63;
  const int rA = tid >> 2, qk = tid & 3;

  f32x4 acc[8] = {};

  for (int kt = 0; kt < 16; ++kt) {     // K = 512
    const unsigned long long* rp = (const unsigned long long*)(
        ring + ((size_t)(dirp * 32 + tslot) * BB + bh * 64 + rA) * HH + kt * 32 + qk * 8);
    unsigned long long r0 = __hip_atomic_load(rp, __ATOMIC_RELAXED, AGENT);
    unsigned long long r1 = __hip_atomic_load(rp + 1, __ATOMIC_RELAXED, AGENT);
    uint4 ra = make_uint4((uint32_t)r0, (uint32_t)(r0 >> 32),
                          (uint32_t)r1, (uint32_t)(r1 >> 32));
    uint4 rb[2];
#pragma unroll
    for (int it = 0; it < 2; ++it) {
      int c = it * 256 + tid;
      int rB = c >> 2, qB = c & 3;
      rb[it] = *(const uint4*)(WoB + (size_t)rB * 1024 + dirp * HH + kt * 32 + qB * 8);
    }
    __syncthreads();
    *(uint4*)((char*)As + rA * 64 + ((qk << 4) ^ ((rA & 3) << 4))) = ra;
#pragma unroll
    for (int it = 0; it < 2; ++it) {
      int c = it * 256 + tid;
      int rB = c >> 2, qB = c & 3;
      *(uint4*)((char*)Bs + rB * 64 + ((qB << 4) ^ ((rB & 3) << 4))) = rb[it];
    }
    __syncthreads();
    const int kb = (lane >> 4) << 4;
    const int rowa = wm * 16 + (lane & 15);
    bf16x8 a = *(const bf16x8*)((const char*)As + rowa * 64 + (kb ^ ((rowa & 3) << 4)));
#pragma unroll
    for (int n = 0; n < 8; ++n) {
      int rowb = n * 16 + (lane & 15);
      bf16x8 b = *(const bf16x8*)((const char*)Bs + rowb * 64 + (kb ^ ((rowb & 3) << 4)));
      acc[n] = __builtin_amdgcn_mfma_f32_16x16x32_bf16(a, b, acc[n], 0, 0, 0);
    }
  }

  const int rbase = (lane >> 4) * 4;
#pragma unroll
  for (int n = 0; n < 8; ++n) {
    int v = n * 16 + (lane & 15);
    float bo = bout[v];
#pragma unroll
    for (int r = 0; r < 4; ++r) {
      int b = bh * 64 + wm * 16 + rbase + r;
      size_t o = ((size_t)b * TT + tp) * VV + v;
      if (mode) (void)unsafeAtomicAdd(&out[o], acc[n][r]);
      else      __hip_atomic_store(&out[o], acc[n][r] + bo, __ATOMIC_RELAXED, AGENT);
    }
  }
}

// ---------------------------------------------------------------------------
// Persistent dual-direction LSTM layer. 128 WGs = (q 4)(nb16 32), 256 thr.
// WG owns rows q*32..+32 x units nb16*16..+16, BOTH dirs, ticked alternately.
// waves (mt, kh): mt = m-tile (16 rows), kh = h plane (0 hi / 1 lo).
// ---------------------------------------------------------------------------
template <int IS_L0, int XKS>
__global__ __launch_bounds__(256, 1) void lstm_persist(
    const ushort* __restrict__ Wh,    // [2][32][16][4][512] Whh frags
    const ushort* __restrict__ Wx,    // [2][32][XKS][4][512] Wih frags (global)
    ushort* __restrict__ hseq,        // [T][B][1024]: L0 writes, L1 x-in
    const int* __restrict__ sent,     // L0: [B][T]
    const ushort* __restrict__ embB,  // L0: [128][256]
    char* __restrict__ hpkB,          // [2 par][2 dir][4 q][2 pl][32][512] bf16
    ushort* __restrict__ ring,        // L1: [2][32][B][512]
    const ushort* __restrict__ WoB,   // L1: [V][1024]
    const float* __restrict__ bout,
    float* __restrict__ out,          // L1: [B][T][V]
    const float* __restrict__ bih, const float* __restrict__ bhh,
    unsigned int* __restrict__ bars,
    char* __restrict__ xw) {          // L1: [128 wg][8 slot][2 dir][8KB]
  const int wg = blockIdx.x;
  const int nb16 = wg & 31;
  const int q = wg >> 5;
  const int tid = threadIdx.x;
  const int wm = tid >> 6;
  const int lane = tid & 63;
  const int mt = wm & 1;
  const int kh = wm >> 1;
  const int col = lane & 15;
  const int ksub = lane >> 4;
  const int arl = mt * 16 + col;        // local row 0..31
  const int grow = q * 32 + arl;        // global batch row (A operand)
  const int er = tid >> 3, eq = tid & 7;  // epilogue ownership

  __shared__ __align__(16) char smem[148480];   // 128KB Whh + 17.4KB exch/proj
  float* exch = (float*)(smem + 131072);        // [2 kh][32 rows][68]

  // ---- preload Whh frags, both dirs (64KB each), once
#pragma unroll
  for (int dd = 0; dd < 2; ++dd) {
    const uint4* src = (const uint4*)(Wh + (size_t)(dd * 32 + nb16) * 32768);
    for (int i = tid; i < 4096; i += 256)
      ((uint4*)(smem + dd * 65536))[i] = src[i];
  }
  __syncthreads();

  // biases: MFMA C-layout (col) for acc init; gate g of unit nb16*16+col
  float biasv[2][4];
#pragma unroll
  for (int d = 0; d < 2; ++d)
#pragma unroll
    for (int g = 0; g < 4; ++g)
      biasv[d][g] = bih[d * 2048 + g * 512 + nb16 * 16 + col] +
                    bhh[d * 2048 + g * 512 + nb16 * 16 + col];

  float cF0 = 0.f, cF1 = 0.f, cB0 = 0.f, cB1 = 0.f;  // c-state
  unsigned int* gslot = bars + 256;
  unsigned int* pslot = bars + 384;
  unsigned int pcount = 0;

  f32x4 aF[4], aB[4];

  // ---- h-part: acc[g] += Whh_g * h_plane(kh); sc1 u64 batched (r9-proven)
  auto h_phase = [&](int dir, int par, f32x4* acc) {
    const unsigned long long* hb = (const unsigned long long*)(
        hpkB + ((size_t)((((par * 2 + dir) * 4 + q) * 2) + kh) << 15)) +
        (size_t)arl * 128 + ksub * 2;
    unsigned long long a0[16], a1[16];
#pragma unroll
    for (int ks = 0; ks < 16; ++ks) {
      a0[ks] = __hip_atomic_load(hb + ks * 8, __ATOMIC_RELAXED, AGENT);
      a1[ks] = __hip_atomic_load(hb + ks * 8 + 1, __ATOMIC_RELAXED, AGENT);
    }
#pragma unroll
    for (int ks = 0; ks < 16; ++ks) {
      uint4 u = make_uint4((uint32_t)a0[ks], (uint32_t)(a0[ks] >> 32),
                           (uint32_t)a1[ks], (uint32_t)(a1[ks] >> 32));
#pragma unroll
      for (int g = 0; g < 4; ++g) {
        bf16x8 b = *(const bf16x8*)(smem + ((size_t)((dir * 16 + ks) * 4 + g) << 10) +
                                    (lane << 4));
        acc[g] = __builtin_amdgcn_mfma_f32_16x16x32_bf16(bc8u(u), b, acc[g], 0, 0, 0);
      }
    }
  };

  auto exch_write = [&](const f32x4* acc) {
#pragma unroll
    for (int g = 0; g < 4; ++g)
#pragma unroll
      for (int r = 0; r < 4; ++r)
        exch[(kh * 32 + mt * 16 + ksub * 4 + r) * 68 + g * 16 + col] = acc[g][r];
  };

  // ---- epilogue: thread (er, eq) owns row er, units 2eq..2eq+1
  auto epi = [&](int dir, int t, int par2, float& c0, float& c1) {
    const float* e0 = exch + er * 68;
    const float* e1 = exch + (32 + er) * 68;
    ushort hh[2], hl[2];
#pragma unroll
    for (int j = 0; j < 2; ++j) {
      int uc = 2 * eq + j;
      float gi = e0[uc] + e1[uc];
      float gf = e0[16 + uc] + e1[16 + uc];
      float gg = e0[32 + uc] + e1[32 + uc];
      float go = e0[48 + uc] + e1[48 + uc];
      float si = sigm(gi), sf = sigm(gf), tg = tanh_f(gg), so = sigm(go);
      float& c = j ? c1 : c0;
      c = sf * c + si * tg;
      float h = so * tanh_f(c);
      hh[j] = f2bf(h);
      hl[j] = f2bf(h - bf2f(hh[j]));
    }
    uint32_t vhi = (uint32_t)hh[0] | ((uint32_t)hh[1] << 16);
    uint32_t vlo = (uint32_t)hl[0] | ((uint32_t)hl[1] << 16);
    char* hw = hpkB + ((size_t)((par2 * 2 + dir) * 4 + q) << 16);
    int off = er * 1024 + (nb16 * 16 + 2 * eq) * 2;
    __hip_atomic_store((uint32_t*)(hw + off), vhi, __ATOMIC_RELAXED, AGENT);
    __hip_atomic_store((uint32_t*)(hw + 32768 + off), vlo, __ATOMIC_RELAXED, AGENT);
    int growr = q * 32 + er;
    if constexpr (IS_L0) {
      ((uint32_t*)hseq)[((size_t)t * BB + growr) * 512 + dir * 256 + nb16 * 8 + eq] = vhi;
    } else {
      __hip_atomic_store((uint32_t*)ring +
                             ((size_t)(dir * 32 + (t & 31)) * BB + growr) * 256 +
                             nb16 * 8 + eq,
                         vhi, __ATOMIC_RELAXED, AGENT);
    }
  };

  // ---- L0 inline x-phase (Wih0 slices L2-hot; no invalidates in this kernel)
  auto x_phase0 = [&](int dir, int t, f32x4* acc) {
#pragma unroll
    for (int g = 0; g < 4; ++g) {
      float b = (kh == 0) ? biasv[dir][g] : 0.f;
      acc[g] = (f32x4){b, b, b, b};
    }
    int v = sent[grow * TT + t];
    const ushort* xr = embB + v * 256;
    const ushort* wx = Wx + ((size_t)(dir * 32 + nb16) * XKS) * 2048;
#pragma unroll
    for (int xx = 0; xx < XKS / 2; ++xx) {
      int ks = kh * (XKS / 2) + xx;
      uint4 ua = *(const uint4*)(xr + ks * 32 + ksub * 8);
#pragma unroll
      for (int g = 0; g < 4; ++g) {
        bf16x8 wb = *(const bf16x8*)(wx + (size_t)(ks * 4 + g) * 512 + lane * 8);
        acc[g] = __builtin_amdgcn_mfma_f32_16x16x32_bf16(bc8u(ua), wb, acc[g], 0, 0, 0);
      }
    }
  };

  // ---- L1 bulk x-precompute: 8 steps/window; install step sbase into acc,
  //      store sbase+1..+7 as bf16 partials to xw (same-thread r/w).
  auto bulk_xw = [&](int dir, int sbase, f32x4* acc) {
    const ushort* wx = Wx + ((size_t)(dir * 32 + nb16) * XKS) * 2048;
#pragma unroll
    for (int gp = 0; gp < 2; ++gp) {
      f32x4 ax[8][2];
#pragma unroll
      for (int i = 0; i < 8; ++i) {
        float b0 = (kh == 0) ? biasv[dir][2 * gp] : 0.f;
        float b1 = (kh == 0) ? biasv[dir][2 * gp + 1] : 0.f;
        ax[i][0] = (f32x4){b0, b0, b0, b0};
        ax[i][1] = (f32x4){b1, b1, b1, b1};
      }
#pragma unroll 2
      for (int xx = 0; xx < 16; ++xx) {
        int ks = kh * 16 + xx;
        bf16x8 w0 = *(const bf16x8*)(wx + (size_t)(ks * 4 + 2 * gp) * 512 + lane * 8);
        bf16x8 w1 = *(const bf16x8*)(wx + (size_t)(ks * 4 + 2 * gp + 1) * 512 + lane * 8);
#pragma unroll
        for (int i = 0; i < 8; ++i) {
          int sp = sbase + i;
          int t = dir ? (TT - 1 - sp) : sp;
          uint4 ua = *(const uint4*)(hseq + ((size_t)t * BB + grow) * 1024 +
                                     ks * 32 + ksub * 8);
          ax[i][0] = __builtin_amdgcn_mfma_f32_16x16x32_bf16(bc8u(ua), w0, ax[i][0], 0, 0, 0);
          ax[i][1] = __builtin_amdgcn_mfma_f32_16x16x32_bf16(bc8u(ua), w1, ax[i][1], 0, 0, 0);
        }
      }
      acc[2 * gp] = ax[0][0];
      acc[2 * gp + 1] = ax[0][1];
#pragma unroll
      for (int i = 1; i < 8; ++i) {
        uint32_t u0 = (uint32_t)f2bf(ax[i][0][0]) | ((uint32_t)f2bf(ax[i][0][1]) << 16);
        uint32_t u1 = (uint32_t)f2bf(ax[i][0][2]) | ((uint32_t)f2bf(ax[i][0][3]) << 16);
        uint32_t u2 = (uint32_t)f2bf(ax[i][1][0]) | ((uint32_t)f2bf(ax[i][1][1]) << 16);
        uint32_t u3 = (uint32_t)f2bf(ax[i][1][2]) | ((uint32_t)f2bf(ax[i][1][3]) << 16);
        *(uint4*)(xw + (((size_t)wg * 8 + ((sbase + i) & 7)) * 2 + dir) * 8192 +
                  tid * 32 + gp * 16) = make_uint4(u0, u1, u2, u3);
      }
    }
  };

  auto unpk = [](uint32_t a, uint32_t b) {
    f32x4 r;
    r[0] = __builtin_bit_cast(float, a << 16);
    r[1] = __builtin_bit_cast(float, a & 0xffff0000u);
    r[2] = __builtin_bit_cast(float, b << 16);
    r[3] = __builtin_bit_cast(float, b & 0xffff0000u);
    return r;
  };
  auto x_phase1 = [&](int dir, int sp, f32x4* acc) {
    const uint4* p = (const uint4*)(xw + (((size_t)wg * 8 + (sp & 7)) * 2 + dir) * 8192 +
                                    tid * 32);
    uint4 v0 = p[0], v1 = p[1];
    acc[0] = unpk(v0.x, v0.y);
    acc[1] = unpk(v0.z, v0.w);
    acc[2] = unpk(v1.x, v1.y);
    acc[3] = unpk(v1.z, v1.w);
  };

  auto wait_dir = [&](int dir, unsigned s) {
    if (tid < 32) {
      const unsigned* sl = bars + dir * 128 + q * 32;
      while (true) {
        unsigned v = __hip_atomic_load(sl + tid, __ATOMIC_RELAXED, AGENT);
        if (__all((int)(v >= s))) break;
        __builtin_amdgcn_s_sleep(1);
      }
    }
    __syncthreads();
  };

  // ---- prologue: accs for step 0, both dirs
  if constexpr (IS_L0) {
    x_phase0(0, 0, aF);
    x_phase0(1, TT - 1, aB);
  } else {
    bulk_xw(0, 0, aF);
    bulk_xw(1, 0, aB);
  }

  // ---- tick loop: each tick advances fwd step s then bwd step s
  for (int s = 0; s < TT; ++s) {
    // ====== FWD (t = s) ======
    wait_dir(0, (unsigned)s);
    h_phase(0, s & 1, aF);
    exch_write(aF);
    __syncthreads();
    epi(0, s, (s & 1) ^ 1, cF0, cF1);
    __syncthreads();  // drain sc1 stores + exch reads
    if (tid == 0)
      __hip_atomic_store(bars + q * 32 + nb16, (unsigned)(s + 1), __ATOMIC_RELAXED, AGENT);

    // ====== BWD (t = TT-1-s) ======
    wait_dir(1, (unsigned)s);
    h_phase(1, s & 1, aB);
    exch_write(aB);
    __syncthreads();
    epi(1, TT - 1 - s, (s & 1) ^ 1, cB0, cB1);
    __syncthreads();
    if (tid == 0)
      __hip_atomic_store(bars + 128 + q * 32 + nb16, (unsigned)(s + 1), __ATOMIC_RELAXED,
                         AGENT);

    // ====== shadow: x for step s+1 ======
    if (s + 1 < TT) {
      if constexpr (IS_L0) {
        x_phase0(0, s + 1, aF);
        x_phase0(1, TT - 2 - s, aB);
      } else {
        if (((s + 1) & 7) == 0) {
          bulk_xw(0, s + 1, aF);
          bulk_xw(1, s + 1, aB);
        } else {
          x_phase1(0, s + 1, aF);
          x_phase1(1, s + 1, aB);
        }
      }
    }

    // ====== projection every 32 ticks (L1) ======
    if constexpr (!IS_L0) {
      if ((s & 31) == 31) {
        if (tid == 0)
          __hip_atomic_store(gslot + wg, (unsigned)(s + 1), __ATOMIC_RELAXED, AGENT);
        if (tid < 128) {
          while (__hip_atomic_load(gslot + tid, __ATOMIC_RELAXED, AGENT) < (unsigned)(s + 1))
            __builtin_amdgcn_s_sleep(1);
        }
        __syncthreads();
        proj_body(s >> 5, wg, tid, ring, WoB, bout, out, smem + 131072);
        __syncthreads();  // proj loads done before ring reuse
        ++pcount;
        if (tid == 0)
          __hip_atomic_store(pslot + wg, pcount, __ATOMIC_RELAXED, AGENT);
        if (tid < 128) {
          while (__hip_atomic_load(pslot + tid, __ATOMIC_RELAXED, AGENT) < pcount)
            __builtin_amdgcn_s_sleep(1);
        }
        __syncthreads();
      }
    }
  }
}

// ---------------------------------------------------------------------------
extern "C" void kernel_launch(void* const* d_in, const int* in_sizes, int n_in,
                              void* d_out, int out_size, void* d_ws, size_t ws_size,
                              hipStream_t stream) {
  const int* sent = (const int*)d_in[0];
  const float* emb = (const float*)d_in[1];
  const float* Wih0 = (const float*)d_in[2];
  const float* Whh0 = (const float*)d_in[3];
  const float* bih0 = (const float*)d_in[4];
  const float* bhh0 = (const float*)d_in[5];
  const float* Wih1 = (const float*)d_in[6];
  const float* Whh1 = (const float*)d_in[7];
  const float* bih1 = (const float*)d_in[8];
  const float* bhh1 = (const float*)d_in[9];
  const float* Wout = (const float*)d_in[10];
  const float* bout = (const float*)d_in[11];
  float* out = (float*)d_out;

  // ws layout (bytes); total 178,587,648
  const size_t NEED = 178587648;
  if (ws_size < NEED) {
    report_ws<<<(out_size + 255) / 256, 256, 0, stream>>>(out, out_size,
                                                          (float)(ws_size >> 20));
    return;
  }
  char* ws = (char*)d_ws;
  ushort* h0   = (ushort*)(ws + 0);                 // 134,217,728  [T][B][1024]
  ushort* Wh0  = (ushort*)(ws + 134217728);         //   4,194,304  Whh0 frags
  ushort* Wh1  = (ushort*)(ws + 138412032);         //   4,194,304  Whh1 frags
  char*   xw   = (char*)(ws + 142606336);           //  16,777,216  (front 2MB = Wx0, L0-only)
  ushort* Wx0  = (ushort*)(ws + 142606336);         //   2,097,152  Wih0 frags (aliased)
  ushort* Wx1  = (ushort*)(ws + 159383552);         //   8,388,608  Wih1 frags
  ushort* WoB  = (ushort*)(ws + 167772160);         //     262,144
  ushort* embB = (ushort*)(ws + 168034304);         //      65,536
  char*   hpk  = (char*)(ws + 168099840);           //   2,097,152
  ushort* ring = (ushort*)(ws + 170196992);         //   8,388,608  [2][32][B][512]
  unsigned int* bars = (unsigned int*)(ws + 178585600);  // 2048B (512 u32)

  pack_emb<<<128, 256, 0, stream>>>(emb, embB);
  pack_w<<<8192, 256, 0, stream>>>(Whh0, Wh0, 16, 512);
  pack_w<<<8192, 256, 0, stream>>>(Whh1, Wh1, 16, 512);
  pack_w<<<4096, 256, 0, stream>>>(Wih0, Wx0, 8, 256);
  pack_w<<<16384, 256, 0, stream>>>(Wih1, Wx1, 32, 1024);
  pack_wout<<<512, 256, 0, stream>>>(Wout, WoB);

  // layer 0 (persistent dual-dir, 128 WGs; no proj)
  zero_h<<<512, 256, 0, stream>>>((unsigned int*)hpk, bars);
  lstm_persist<1, 8><<<128, 256, 0, stream>>>(
      Wh0, Wx0, h0, sent, embB, hpk, ring, WoB, bout, out, bih0, bhh0, bars, xw);

  // layer 1 (persistent dual-dir, proj folded in)
  zero_h<<<512, 256, 0, stream>>>((unsigned int*)hpk, bars);
  lstm_persist<0, 32><<<128, 256, 0, stream>>>(
      Wh1, Wx1, h0, sent, embB, hpk, ring, WoB, bout, out, bih1, bhh1, bars, xw);
}

// Round 13
// 11238.688 us; speedup vs baseline: 1.6914x; 1.6914x over previous
//
#include <hip/hip_runtime.h>
#include <stdint.h>

// ---------------------------------------------------------------------------
// 2-layer BiLSTM LM: emb -> BiLSTM(E=256->H=512) -> BiLSTM(1024->512) -> proj
// V=128 E=256 H=512 B=128 T=512.
//
// Round 13: rollback to r10 (best, 11.0ms) + WITHIN-ROUND A/B decomposition.
//  r12 post-mortem: dual-dir-in-one-WG serialized both chains + half chip ->
//  regression. r10's 13us/step is 4x my component model; candidates are
//  (a) barrier detect + straggler max over 128 WGs, (b) coherence path,
//  (c) intrinsic LLC drain->observe chain. To isolate at ZERO added cost,
//  each layer is split into two 256-step dispatches (c-state spilled to
//  scratch between; identical real work), varying ONE mechanism per pair:
//   L0: D1 = ACQUIRE-inv + plain h loads (r10)  vs  D2 = sc1 h, no inv (r9)
//   L1: D1 = scope-128 + sleep-poll (r10)       vs  D2 = scope-64 + busy-poll
//  rocprof per-dispatch durations give the four cells directly.
//
// Numerics (validated r1..r10, absmax 1.95e-3): bf16 MFMA fp32-accum; c f32;
// h carried as hi/lo bf16 planes; gates = Whh*(hi+lo) + Wih*x + b.
// ---------------------------------------------------------------------------

#define TT 512
#define BB 128
#define HH 512
#define VV 128
#define AGENT __HIP_MEMORY_SCOPE_AGENT

typedef __attribute__((ext_vector_type(8))) short bf16x8;
typedef __attribute__((ext_vector_type(4))) float f32x4;

__device__ __forceinline__ ushort f2bf(float f) {
  uint32_t u = __builtin_bit_cast(uint32_t, f);
  u += 0x7FFFu + ((u >> 16) & 1u);
  return (ushort)(u >> 16);
}
__device__ __forceinline__ float bf2f(ushort h) {
  uint32_t u = ((uint32_t)h) << 16;
  return __builtin_bit_cast(float, u);
}
__device__ __forceinline__ float sigm(float x) { return 1.f / (1.f + __expf(-x)); }
__device__ __forceinline__ float tanh_f(float x) { return 1.f - 2.f / (__expf(2.f * x) + 1.f); }
__device__ __forceinline__ bf16x8 bc8u(uint4 u) { return __builtin_bit_cast(bf16x8, u); }

__global__ __launch_bounds__(256) void report_ws(float* __restrict__ out, int n, float val) {
  int i = blockIdx.x * 256 + threadIdx.x;
  if (i < n) out[i] = val;
}

__global__ __launch_bounds__(256) void pack_emb(const float* __restrict__ emb,
                                                ushort* __restrict__ embB) {
  int i = blockIdx.x * 256 + threadIdx.x;  // 32768
  embB[i] = f2bf(emb[i]);
}

// Frag-packed W (r9/r10 layout). Slice (d, nb) = 2*KSL frags of 1KB.
// frag f = kslg*2 + n2; elem (l,e): rloc = n2*16 + (l&15);
// grow = (rloc>>3)*512 + nb*8 + (rloc&7); k = kslg*32 + (l>>4)*8 + e.
// k<512 -> Whh[d][grow][k]; else Wih[d][grow][k-512].
__global__ __launch_bounds__(256) void pack_w(const float* __restrict__ Whh,
                                              const float* __restrict__ Wih,
                                              ushort* __restrict__ Wp,
                                              int KSL, int Ein) {
  size_t idx = (size_t)blockIdx.x * 256 + threadIdx.x;
  size_t total = (size_t)128 * 2 * KSL * 512;
  if (idx >= total) return;
  int e = (int)(idx & 7);
  int l = (int)((idx >> 3) & 63);
  int f = (int)((idx >> 9) % (size_t)(2 * KSL));
  int sl = (int)(idx / ((size_t)1024 * KSL));
  int nb = sl & 63, d = sl >> 6;
  int n2 = f & 1, kslg = f >> 1;
  int rloc = n2 * 16 + (l & 15);
  int grow = (rloc >> 3) * 512 + nb * 8 + (rloc & 7);
  int k = kslg * 32 + (l >> 4) * 8 + e;
  float val;
  if (k < 512) val = Whh[((size_t)d * 2048 + grow) * 512 + k];
  else         val = Wih[((size_t)d * 2048 + grow) * Ein + (k - 512)];
  Wp[idx] = f2bf(val);
}

__global__ __launch_bounds__(256) void pack_wout(const float* __restrict__ Wo,
                                                 ushort* __restrict__ WoB) {
  int i = blockIdx.x * 256 + threadIdx.x;  // 131072
  WoB[i] = f2bf(Wo[i]);
}

// zero hpk (1MB = 65536 uint4) + barrier slots (512 u32)
__global__ __launch_bounds__(256) void zero_h(unsigned int* __restrict__ hpk,
                                              unsigned int* __restrict__ bars) {
  int i = blockIdx.x * 256 + threadIdx.x;  // grid 256
  ((uint4*)hpk)[i] = make_uint4(0, 0, 0, 0);
  if (i < 512) bars[i] = 0;
}

// ---------------------------------------------------------------------------
// Projection chunk (r10-validated): WG -> t = base(dirp, k)+slot, rows
// bh*64..+63, all 128 v, K=512. k<=3: write (+bout); k>=4: atomic add.
// ---------------------------------------------------------------------------
__device__ void proj_body(int k, int slot, int dirp, int bh, int tid,
                          const ushort* __restrict__ ring,
                          const ushort* __restrict__ WoB,
                          const float* __restrict__ bout,
                          float* __restrict__ out, char* shm) {
  const int tp = (dirp ? (448 - 64 * k) : (64 * k)) + slot;
  const int mode = (k >= 4);
  ushort* As = (ushort*)shm;            // [64][32] swizzled 64B rows
  ushort* Bs = (ushort*)(shm + 4096);   // [128][32] swizzled
  const int wm = tid >> 6;
  const int lane = tid & 63;

  f32x4 acc[8] = {};

  for (int kt = 0; kt < 16; ++kt) {     // K = 512
    const int rA = tid >> 2, qA = tid & 3;
    uint4 ra = *(const uint4*)(ring + ((size_t)(dirp * 64 + slot) * BB + bh * 64 + rA) * HH +
                               kt * 32 + qA * 8);
    uint4 rb[2];
#pragma unroll
    for (int it = 0; it < 2; ++it) {
      int c = it * 256 + tid;
      int rB = c >> 2, qB = c & 3;
      rb[it] = *(const uint4*)(WoB + (size_t)rB * 1024 + dirp * HH + kt * 32 + qB * 8);
    }
    __syncthreads();
    *(uint4*)((char*)As + rA * 64 + ((qA << 4) ^ ((rA & 3) << 4))) = ra;
#pragma unroll
    for (int it = 0; it < 2; ++it) {
      int c = it * 256 + tid;
      int rB = c >> 2, qB = c & 3;
      *(uint4*)((char*)Bs + rB * 64 + ((qB << 4) ^ ((rB & 3) << 4))) = rb[it];
    }
    __syncthreads();
    const int kb = (lane >> 4) << 4;
    const int rowa = wm * 16 + (lane & 15);
    bf16x8 a = *(const bf16x8*)((const char*)As + rowa * 64 + (kb ^ ((rowa & 3) << 4)));
#pragma unroll
    for (int n = 0; n < 8; ++n) {
      int rowb = n * 16 + (lane & 15);
      bf16x8 b = *(const bf16x8*)((const char*)Bs + rowb * 64 + (kb ^ ((rowb & 3) << 4)));
      acc[n] = __builtin_amdgcn_mfma_f32_16x16x32_bf16(a, b, acc[n], 0, 0, 0);
    }
  }

  const int rbase = (lane >> 4) * 4;
#pragma unroll
  for (int n = 0; n < 8; ++n) {
    int v = n * 16 + (lane & 15);
    float bo = bout[v];
#pragma unroll
    for (int r = 0; r < 4; ++r) {
      int b = bh * 64 + wm * 16 + rbase + r;
      size_t o = ((size_t)b * TT + tp) * VV + v;
      if (mode) (void)unsafeAtomicAdd(&out[o], acc[n][r]);
      else      __hip_atomic_store(&out[o], acc[n][r] + bo, __ATOMIC_RELAXED, AGENT);
    }
  }
}

// ---------------------------------------------------------------------------
// Persistent LSTM layer segment [s0, s1). 256 WGs = (dir 2)(nb 64)(mh 2).
// HMODE 0: per-step ACQUIRE (L2 inv) + plain uint4 h loads   (r10)
// HMODE 1: no inv; sc1 u64 atomic h loads                     (r9)
// BMODE 0: wait on dir's 128 slots, s_sleep(1) poll           (r10)
// BMODE 1: wait on same-(dir,mh) 64 slots, busy poll
// c-state spilled to cbuf at s1<TT, reloaded at s0>0.
// ---------------------------------------------------------------------------
template <int IS_L0, int XS, int KSL, int HMODE, int BMODE>
__global__ __launch_bounds__(256, 1) void lstm_persist(
    const ushort* __restrict__ Wp,    // [128 slices][2*KSL frags][512]
    ushort* __restrict__ hseq,        // [T][B][1024]: L0 writes (sc1), L1 x-in
    const int* __restrict__ sent,     // L0: [B][T]
    const ushort* __restrict__ embB,  // L0: [128][256]
    unsigned int* __restrict__ hpk,   // [2 par][2 dir][2 pl][128][256] u32
    ushort* __restrict__ ring,        // L1: [2][64][B][512]
    const ushort* __restrict__ WoB,   // L1: [V][1024]
    const float* __restrict__ bout,   // L1: [V]
    float* __restrict__ out,          // L1: [B][T][V]
    const float* __restrict__ bih, const float* __restrict__ bhh,
    unsigned int* __restrict__ bars,
    float* __restrict__ cbuf,         // [256 wg][256 thr][2] f32
    int s0, int s1) {
  const int wg = blockIdx.x;          // (dir<<7) | (nb<<1) | mh
  const int mh = wg & 1;
  const int nb = (wg >> 1) & 63;
  const int dir = wg >> 7;
  const int tid = threadIdx.x;
  const int wm = tid >> 6;
  const int lane = tid & 63;

  __shared__ __align__(16) char smem[KSL * 2048 + 12544];

  // ---- preload full W slice into LDS
  {
    const uint4* wsrc = (const uint4*)(Wp + (size_t)(dir * 64 + nb) * (2 * KSL * 512));
    for (int i = tid; i < KSL * 128; i += 256)
      ((uint4*)smem)[i] = wsrc[i];
  }
  __syncthreads();

  float* exch = (float*)(smem + KSL * 2048);   // [64][33] f32

  const int arow = mh * 64 + wm * 16 + (lane & 15);  // global batch row (A)
  const int ksub = lane >> 4;

  const int ju = nb * 8 + (lane & 7);
  const float biJ = bih[dir * 2048 + ju] + bhh[dir * 2048 + ju];
  const float bfJ = bih[dir * 2048 + 512 + ju] + bhh[dir * 2048 + 512 + ju];
  const float bgJ = bih[dir * 2048 + 1024 + ju] + bhh[dir * 2048 + 1024 + ju];
  const float boJ = bih[dir * 2048 + 1536 + ju] + bhh[dir * 2048 + 1536 + ju];
  const float bias0 = (lane & 8) ? bfJ : biJ;
  const float bias1 = (lane & 8) ? boJ : bgJ;

  float cst0, cst1;                     // c for (row tid>>2, units 2q, 2q+1)
  if (s0 == 0) {
    cst0 = 0.f; cst1 = 0.f;
  } else {
    const float* cp = cbuf + ((size_t)wg * 256 + tid) * 2;
    cst0 = cp[0]; cst1 = cp[1];
  }
  unsigned int* stepslot = bars;        // [256]
  unsigned int* pslot = bars + 256;     // [256]

  f32x4 acc0, acc1;

  // x-part: acc = bias + x(t) @ Wih^T
  auto x_phase = [&](int t) {
    acc0 = (f32x4){bias0, bias0, bias0, bias0};
    acc1 = (f32x4){bias1, bias1, bias1, bias1};
    const ushort* xr;
    if constexpr (IS_L0) xr = embB + sent[arow * TT + t] * 256 + ksub * 8;
    else                 xr = hseq + ((size_t)t * BB + arow) * 1024 + ksub * 8;
    uint4 xa[XS];
#pragma unroll
    for (int i = 0; i < XS; ++i) xa[i] = *(const uint4*)(xr + i * 32);
#pragma unroll
    for (int i = 0; i < XS; ++i) {
      bf16x8 b0 = *(const bf16x8*)(smem + (16 + i) * 2048 + (lane << 4));
      bf16x8 b1 = *(const bf16x8*)(smem + (16 + i) * 2048 + 1024 + (lane << 4));
      acc0 = __builtin_amdgcn_mfma_f32_16x16x32_bf16(bc8u(xa[i]), b0, acc0, 0, 0, 0);
      acc1 = __builtin_amdgcn_mfma_f32_16x16x32_bf16(bc8u(xa[i]), b1, acc1, 0, 0, 0);
    }
  };

  // h-part: acc += Whh*(hi + lo)
  auto h_phase = [&](int par) {
    uint4 ahi[16], alo[16];
    if constexpr (HMODE == 0) {         // plain loads (L2-served post-inv)
      const uint4* hb = (const uint4*)hpk + (size_t)par * 32768 + (size_t)dir * 16384 +
                        (size_t)arow * 64 + ksub;
#pragma unroll
      for (int ks = 0; ks < 16; ++ks) ahi[ks] = hb[ks * 4];
#pragma unroll
      for (int ks = 0; ks < 16; ++ks) alo[ks] = hb[8192 + ks * 4];
    } else {                            // sc1 u64 atomic loads (LLC-served)
      const unsigned long long* hb64 = (const unsigned long long*)hpk +
                                       (size_t)par * 65536 + (size_t)dir * 32768 +
                                       (size_t)arow * 128 + ksub * 2;
#pragma unroll
      for (int ks = 0; ks < 16; ++ks) {
        unsigned long long a0 = __hip_atomic_load(hb64 + ks * 8, __ATOMIC_RELAXED, AGENT);
        unsigned long long a1 = __hip_atomic_load(hb64 + ks * 8 + 1, __ATOMIC_RELAXED, AGENT);
        ahi[ks] = make_uint4((uint32_t)a0, (uint32_t)(a0 >> 32),
                             (uint32_t)a1, (uint32_t)(a1 >> 32));
      }
#pragma unroll
      for (int ks = 0; ks < 16; ++ks) {
        unsigned long long a0 =
            __hip_atomic_load(hb64 + 16384 + ks * 8, __ATOMIC_RELAXED, AGENT);
        unsigned long long a1 =
            __hip_atomic_load(hb64 + 16384 + ks * 8 + 1, __ATOMIC_RELAXED, AGENT);
        alo[ks] = make_uint4((uint32_t)a0, (uint32_t)(a0 >> 32),
                             (uint32_t)a1, (uint32_t)(a1 >> 32));
      }
    }
#pragma unroll
    for (int ks = 0; ks < 16; ++ks) {
      bf16x8 b0 = *(const bf16x8*)(smem + ks * 2048 + (lane << 4));
      bf16x8 b1 = *(const bf16x8*)(smem + ks * 2048 + 1024 + (lane << 4));
      acc0 = __builtin_amdgcn_mfma_f32_16x16x32_bf16(bc8u(ahi[ks]), b0, acc0, 0, 0, 0);
      acc1 = __builtin_amdgcn_mfma_f32_16x16x32_bf16(bc8u(ahi[ks]), b1, acc1, 0, 0, 0);
      acc0 = __builtin_amdgcn_mfma_f32_16x16x32_bf16(bc8u(alo[ks]), b0, acc0, 0, 0, 0);
      acc1 = __builtin_amdgcn_mfma_f32_16x16x32_bf16(bc8u(alo[ks]), b1, acc1, 0, 0, 0);
    }
  };

  // prologue: x-part for step s0
  x_phase(dir ? (TT - 1 - s0) : s0);

  for (int s = s0; s < s1; ++s) {
    const int t = dir ? (TT - 1 - s) : s;

    // ---- wait for h(s)
    if constexpr (BMODE == 0) {         // r10: dir's 128 slots, sleep poll
      if (tid < 128) {
        while (__hip_atomic_load(&stepslot[dir * 128 + tid], __ATOMIC_RELAXED, AGENT) <
               (unsigned)s)
          __builtin_amdgcn_s_sleep(1);
      }
    } else {                            // scope-64 (same dir+mh), busy poll
      if (tid < 64) {
        while (__hip_atomic_load(&stepslot[dir * 128 + (tid << 1) + mh],
                                 __ATOMIC_RELAXED, AGENT) < (unsigned)s) {}
      }
    }
    __syncthreads();
    if constexpr (HMODE == 0) {
      if (tid == 0)
        (void)__hip_atomic_load(&stepslot[wg], __ATOMIC_ACQUIRE, AGENT);
      __syncthreads();
    }

    h_phase(s & 1);

    // ---- gate exchange through LDS [64][33] f32
    {
      const int rb4 = (lane >> 4) * 4;
#pragma unroll
      for (int r = 0; r < 4; ++r) {
        int lr = wm * 16 + rb4 + r;
        exch[lr * 33 + (lane & 15)]      = acc0[r];
        exch[lr * 33 + 16 + (lane & 15)] = acc1[r];
      }
    }
    __syncthreads();

    // ---- epilogue: thread (lr = tid>>2, q = tid&3) owns units 2q, 2q+1
    {
      const int lr = tid >> 2;
      const int q = tid & 3;
      ushort hh[2], hl[2];
#pragma unroll
      for (int i = 0; i < 2; ++i) {
        const int u = q * 2 + i;
        float gi = exch[lr * 33 + u];
        float gf = exch[lr * 33 + 8 + u];
        float gg = exch[lr * 33 + 16 + u];
        float go = exch[lr * 33 + 24 + u];
        float si = sigm(gi), sf = sigm(gf), tg = tanh_f(gg), so = sigm(go);
        float c = sf * (i ? cst1 : cst0) + si * tg;
        (i ? cst1 : cst0) = c;
        float h = so * tanh_f(c);
        hh[i] = f2bf(h);
        hl[i] = f2bf(h - bf2f(hh[i]));
      }
      const int b = mh * 64 + lr;
      const uint32_t vhi = (uint32_t)hh[0] | ((uint32_t)hh[1] << 16);
      const uint32_t vlo = (uint32_t)hl[0] | ((uint32_t)hl[1] << 16);
      unsigned int* hw = hpk + (size_t)((s & 1) ^ 1) * 131072 + (size_t)dir * 65536;
      __hip_atomic_store(hw + (size_t)b * 256 + nb * 4 + q, vhi, __ATOMIC_RELAXED, AGENT);
      __hip_atomic_store(hw + 32768 + (size_t)b * 256 + nb * 4 + q, vlo,
                         __ATOMIC_RELAXED, AGENT);
      if constexpr (IS_L0) {
        __hip_atomic_store((unsigned int*)hseq + ((size_t)t * BB + b) * 512 +
                               dir * 256 + nb * 4 + q,
                           vhi, __ATOMIC_RELAXED, AGENT);
      } else {
        __hip_atomic_store((unsigned int*)ring +
                               ((size_t)(dir * 64 + (t & 63)) * BB + b) * 256 + nb * 4 + q,
                           vhi, __ATOMIC_RELAXED, AGENT);
      }
    }

    __syncthreads();  // drain stores (vmcnt 0) + protect exch
    if (tid == 0)
      __hip_atomic_store(&stepslot[wg], (unsigned)(s + 1), __ATOMIC_RELAXED, AGENT);

    // x-part for step s+1 in the wait shadow
    if (s + 1 < s1) x_phase(dir ? (TT - 2 - s) : (s + 1));

    if constexpr (!IS_L0) {
      if ((s & 63) == 63) {
        // all 256 WGs published this chunk; ACQUIRE (L2 inv) for plain ring reads
        {
          const unsigned tgt = (unsigned)(s + 1);
          while (__hip_atomic_load(&stepslot[tid], __ATOMIC_RELAXED, AGENT) < tgt)
            __builtin_amdgcn_s_sleep(1);
        }
        __syncthreads();
        if (tid == 0) (void)__hip_atomic_load(&stepslot[0], __ATOMIC_ACQUIRE, AGENT);
        __syncthreads();
        proj_body(s >> 6, wg & 63, (wg >> 6) & 1, wg >> 7, tid, ring, WoB, bout, out,
                  smem + KSL * 2048);
        __syncthreads();  // proj loads drained before ring reuse
        const unsigned ptg = (unsigned)((s >> 6) + 1);
        if (tid == 0)
          __hip_atomic_store(pslot + wg, ptg, __ATOMIC_RELAXED, AGENT);
        while (__hip_atomic_load(pslot + tid, __ATOMIC_RELAXED, AGENT) < ptg)
          __builtin_amdgcn_s_sleep(1);
        __syncthreads();
      }
    }
  }

  // ---- spill c-state for the next segment
  if (s1 < TT) {
    float* cp = cbuf + ((size_t)wg * 256 + tid) * 2;
    cp[0] = cst0;
    cp[1] = cst1;
  }
}

// ---------------------------------------------------------------------------
extern "C" void kernel_launch(void* const* d_in, const int* in_sizes, int n_in,
                              void* d_out, int out_size, void* d_ws, size_t ws_size,
                              hipStream_t stream) {
  const int* sent = (const int*)d_in[0];
  const float* emb = (const float*)d_in[1];
  const float* Wih0 = (const float*)d_in[2];
  const float* Whh0 = (const float*)d_in[3];
  const float* bih0 = (const float*)d_in[4];
  const float* bhh0 = (const float*)d_in[5];
  const float* Wih1 = (const float*)d_in[6];
  const float* Whh1 = (const float*)d_in[7];
  const float* bih1 = (const float*)d_in[8];
  const float* bhh1 = (const float*)d_in[9];
  const float* Wout = (const float*)d_in[10];
  const float* bout = (const float*)d_in[11];
  float* out = (float*)d_out;

  // ws layout (bytes); total 171,771,904
  const size_t NEED = 171771904;
  if (ws_size < NEED) {
    report_ws<<<(out_size + 255) / 256, 256, 0, stream>>>(out, out_size,
                                                          (float)(ws_size >> 20));
    return;
  }
  char* ws = (char*)d_ws;
  ushort* h0   = (ushort*)(ws + 0);                 // 134,217,728  [T][B][1024]
  ushort* Wp0  = (ushort*)(ws + 134217728);         //   6,291,456  KSL=24
  ushort* Wp1  = (ushort*)(ws + 140509184);         //  12,582,912  KSL=48
  ushort* WoB  = (ushort*)(ws + 153092096);         //     262,144
  ushort* embB = (ushort*)(ws + 153354240);         //      65,536
  unsigned int* hpk = (unsigned int*)(ws + 153419776); // 1,048,576
  ushort* ring = (ushort*)(ws + 154468352);         //   8,388,608 (of 16MB region)
  unsigned int* bars = (unsigned int*)(ws + 171245568);  // 2048B (512 u32)
  float* cbuf = (float*)(ws + 171247616);           //     524,288

  pack_emb<<<128, 256, 0, stream>>>(emb, embB);
  pack_w<<<12288, 256, 0, stream>>>(Whh0, Wih0, Wp0, 24, 256);
  pack_w<<<24576, 256, 0, stream>>>(Whh1, Wih1, Wp1, 48, 1024);
  pack_wout<<<512, 256, 0, stream>>>(Wout, WoB);

  // ---- layer 0: D1 = inv+plain-h (r10), D2 = sc1-h no-inv (r9)
  zero_h<<<256, 256, 0, stream>>>(hpk, bars);
  lstm_persist<1, 8, 24, 0, 0><<<256, 256, 0, stream>>>(
      Wp0, h0, sent, embB, hpk, ring, WoB, bout, out, bih0, bhh0, bars, cbuf, 0, 256);
  lstm_persist<1, 8, 24, 1, 0><<<256, 256, 0, stream>>>(
      Wp0, h0, sent, embB, hpk, ring, WoB, bout, out, bih0, bhh0, bars, cbuf, 256, 512);

  // ---- layer 1: D1 = scope-128+sleep (r10), D2 = scope-64+busy
  zero_h<<<256, 256, 0, stream>>>(hpk, bars);
  lstm_persist<0, 32, 48, 0, 0><<<256, 256, 0, stream>>>(
      Wp1, h0, sent, embB, hpk, ring, WoB, bout, out, bih1, bhh1, bars, cbuf, 0, 256);
  lstm_persist<0, 32, 48, 0, 1><<<256, 256, 0, stream>>>(
      Wp1, h0, sent, embB, hpk, ring, WoB, bout, out, bih1, bhh1, bars, cbuf, 256, 512);
}